// Round 7
// baseline (451.719 us; speedup 1.0000x reference)
//
#include <hip/hip_runtime.h>
#include <hip/hip_bf16.h>

typedef unsigned short u16;
typedef unsigned long long u64;
typedef u16 us8 __attribute__((ext_vector_type(8)));
typedef __bf16 bf8_t __attribute__((ext_vector_type(8)));
typedef float f32x4 __attribute__((ext_vector_type(4)));
typedef float f32x16 __attribute__((ext_vector_type(16)));

__device__ __forceinline__ float b2f(u16 u) {
    return __uint_as_float(((unsigned int)u) << 16);
}
__device__ __forceinline__ u16 f2b(float f) {
    union { __hip_bfloat16 h; u16 u; } v;
    v.h = __float2bfloat16(f);
    return v.u;
}
__device__ __forceinline__ f32x4 mfma16(bf8_t a, bf8_t b, f32x4 c) {
    return __builtin_amdgcn_mfma_f32_16x16x32_bf16(a, b, c, 0, 0, 0);
}
__device__ __forceinline__ f32x16 mfma32(bf8_t a, bf8_t b, f32x16 c) {
    return __builtin_amdgcn_mfma_f32_32x32x16_bf16(a, b, c, 0, 0, 0);
}
__device__ __forceinline__ void gload_lds16(const u16* g, u16* lds_base) {
    __builtin_amdgcn_global_load_lds((const __attribute__((address_space(1))) unsigned int*)g,
                                     (__attribute__((address_space(3))) unsigned int*)lds_base,
                                     16, 0, 0);
}

// ---------------- fused fp32 -> bf16 convert for all three inputs
__global__ __launch_bounds__(256) void cvt_all(const float* __restrict__ x, const float* __restrict__ wq,
                                               const float* __restrict__ wo, u16* __restrict__ xb,
                                               u16* __restrict__ wqb, u16* __restrict__ wob) {
    int idx = blockIdx.x * 256 + threadIdx.x;   // 3,145,728 groups of 8
    const float* s; u16* d; int off;
    if (idx < 1048576)      { s = x;  d = xb;  off = idx; }
    else if (idx < 2621440) { s = wq; d = wqb; off = idx - 1048576; }
    else                    { s = wo; d = wob; off = idx - 2621440; }
    float4 f0 = ((const float4*)s)[(size_t)off * 2];
    float4 f1 = ((const float4*)s)[(size_t)off * 2 + 1];
    us8 o;
    o[0] = f2b(f0.x); o[1] = f2b(f0.y); o[2] = f2b(f0.z); o[3] = f2b(f0.w);
    o[4] = f2b(f1.x); o[5] = f2b(f1.y); o[6] = f2b(f1.z); o[7] = f2b(f1.w);
    ((us8*)d)[off] = o;
}

// ---------------- 32x32x16 MFMA GEMM: C[m,n] = sum_k A[m,k]*B[n,k]; 128x128x32 tiles
// wave tile = 32 rows x 128 cols (acc[4] f32x16). MODE 0: bf16 out + RoPE on Q/K blocks.
// MODE 1: fp32 out, plain.
#define ROPE_COEF (-0.14391156514261285f)   // -ln(10000)/64
template<int MODE>
__global__ __launch_bounds__(256) void gemm32(const u16* __restrict__ A, const u16* __restrict__ B,
                                              void* __restrict__ Cout, int M, int N, int K, int ldc) {
    __shared__ u16 Alds[128 * 32];
    __shared__ u16 Blds[128 * 32];
    const int tid = threadIdx.x;
    const int lane = tid & 63, wave = tid >> 6;
    const int l31 = lane & 31, kg = lane >> 5;
    const int m0 = blockIdx.y * 128, n0 = blockIdx.x * 128;
    const int srow = lane >> 2;
    const int scol = (lane & 3) * 8;

    f32x16 acc[4] = {};

    for (int k0 = 0; k0 < K; k0 += 32) {
#pragma unroll
        for (int p = 0; p < 2; p++) {
            int rbase = wave * 16 + p * 64;
            gload_lds16(A + (size_t)(m0 + rbase + srow) * K + k0 + scol, &Alds[rbase * 32]);
            gload_lds16(B + (size_t)(n0 + rbase + srow) * K + k0 + scol, &Blds[rbase * 32]);
        }
        __syncthreads();
        bf8_t af[2];
#pragma unroll
        for (int ks = 0; ks < 2; ks++)
            af[ks] = *(const bf8_t*)&Alds[(wave * 32 + l31) * 32 + ks * 16 + kg * 8];
        bf8_t bfr[4][2];
#pragma unroll
        for (int nb = 0; nb < 4; nb++)
#pragma unroll
            for (int ks = 0; ks < 2; ks++)
                bfr[nb][ks] = *(const bf8_t*)&Blds[(nb * 32 + l31) * 32 + ks * 16 + kg * 8];
#pragma unroll
        for (int ks = 0; ks < 2; ks++)
#pragma unroll
            for (int nb = 0; nb < 4; nb++)
                acc[nb] = mfma32(af[ks], bfr[nb][ks], acc[nb]);
        __syncthreads();
    }

    if (MODE == 0) {
        // RoPE on Q/K col-blocks: this 128-col block is one (type,h) head slice; pairs (d, d+64)
        // live in acc[nb] / acc[nb+2] of the same thread.
        int type = blockIdx.x >> 4;     // 0=Q 1=K 2=V
        if (type < 2) {
#pragma unroll
            for (int nb = 0; nb < 2; nb++) {
                float j = (float)(nb * 32 + l31);
                float inv = __expf(j * ROPE_COEF);
#pragma unroll
                for (int r = 0; r < 16; r++) {
                    int rl = wave * 32 + (r & 3) + 8 * (r >> 2) + 4 * kg;
                    int s = (m0 + rl) & 2047;
                    float sn, c;
                    __sincosf((float)s * inv, &sn, &c);
                    float x1 = acc[nb][r], x2 = acc[nb + 2][r];
                    acc[nb][r]     = x1 * c - x2 * sn;
                    acc[nb + 2][r] = x2 * c + x1 * sn;
                }
            }
        }
        u16* Co = (u16*)Cout;
#pragma unroll
        for (int nb = 0; nb < 4; nb++)
#pragma unroll
            for (int r = 0; r < 16; r++) {
                int rl = wave * 32 + (r & 3) + 8 * (r >> 2) + 4 * kg;
                Co[(size_t)(m0 + rl) * ldc + n0 + nb * 32 + l31] = f2b(acc[nb][r]);
            }
    } else {
        float* Co = (float*)Cout;
#pragma unroll
        for (int nb = 0; nb < 4; nb++)
#pragma unroll
            for (int r = 0; r < 16; r++) {
                int rl = wave * 32 + (r & 3) + 8 * (r >> 2) + 4 * kg;
                Co[(size_t)(m0 + rl) * ldc + n0 + nb * 32 + l31] = acc[nb][r];
            }
    }
}

// ---------------- V transpose: qkv V part (B,S,H,D) -> VT (B,H,D,S)
__global__ __launch_bounds__(256) void transpose_v(const u16* __restrict__ qkv, u16* __restrict__ VT) {
    __shared__ u16 T[64 * 136];
    const int tid = threadIdx.x;
    const int s0 = blockIdx.x * 64;
    const int bh = blockIdx.y;
    const int b = bh >> 4, h = bh & 15;
#pragma unroll
    for (int p = 0; p < 4; p++) {
        int sl = p * 16 + (tid >> 4);
        int d0 = (tid & 15) * 8;
        *(us8*)&T[sl * 136 + d0] =
            *(const us8*)(qkv + ((size_t)(b * 2048 + s0 + sl)) * 6144 + 4096 + h * 128 + d0);
    }
    __syncthreads();
#pragma unroll
    for (int p = 0; p < 4; p++) {
        int idx = p * 256 + tid;
        int d = idx & 127;
        int sg = idx >> 7;
        us8 v;
#pragma unroll
        for (int i = 0; i < 8; i++) v[i] = T[(sg * 8 + i) * 136 + d];
        *(us8*)&VT[((size_t)bh * 128 + d) * 2048 + s0 + sg * 8] = v;
    }
}

// ---------------- Flash attention v4 (unchanged from round 6)
#define ATT_SCALE 0.08838834764831845f

__global__ __launch_bounds__(256, 2) void attn_flash(const u16* __restrict__ qkv, const u16* __restrict__ VT,
                                                     u16* __restrict__ AO) {
    const int bh = blockIdx.x;
    const int qt = 15 - blockIdx.y;
    const int b = bh >> 4, h = bh & 15;
    const int tid = threadIdx.x, lane = tid & 63, wave = tid >> 6;
    const int lm = lane & 15, lq = lane >> 4;
    const int q0 = qt * 128;

    __shared__ u16 Kt[64 * 136];
    __shared__ u16 Vt[128 * 72];

    bf8_t qf[2][4];
#pragma unroll
    for (int qg = 0; qg < 2; qg++) {
        const u16* Qrow = qkv + ((size_t)(b * 2048 + q0 + qg * 64 + wave * 16 + lm)) * 6144 + h * 128;
#pragma unroll
        for (int ks = 0; ks < 4; ks++)
            qf[qg][ks] = *(const bf8_t*)(Qrow + ks * 32 + lq * 8);
    }

    f32x4 Of[2][8] = {};
    float mrun[2] = {-3.0e38f, -3.0e38f}, lrun[2] = {0.f, 0.f};

    const u16* Kbase = qkv + (size_t)b * 2048 * 6144 + 2048 + h * 128;
    const u16* VTbase = VT + (size_t)bh * 128 * 2048;

    const int krow = tid >> 4;
    const int kcol = (tid & 15) * 8;
    const int vrow = tid >> 3;
    const int vcol = (tid & 7) * 8;
    const int ktmax = 2 * qt + 1;

    us8 kreg[4], vreg[4];
#pragma unroll
    for (int p = 0; p < 4; p++) {
        kreg[p] = *(const us8*)(Kbase + (size_t)(p * 16 + krow) * 6144 + kcol);
        vreg[p] = *(const us8*)(VTbase + (size_t)(p * 32 + vrow) * 2048 + vcol);
    }

    for (int kt = 0; kt <= ktmax; kt++) {
        __syncthreads();
#pragma unroll
        for (int p = 0; p < 4; p++) {
            *(us8*)&Kt[(p * 16 + krow) * 136 + kcol] = kreg[p];
            *(us8*)&Vt[(p * 32 + vrow) * 72 + vcol] = vreg[p];
        }
        __syncthreads();
        {
            int kn = (kt + 1 <= ktmax ? kt + 1 : ktmax) * 64;
#pragma unroll
            for (int p = 0; p < 4; p++) {
                kreg[p] = *(const us8*)(Kbase + (size_t)(kn + p * 16 + krow) * 6144 + kcol);
                vreg[p] = *(const us8*)(VTbase + (size_t)(p * 32 + vrow) * 2048 + kn + vcol);
            }
        }

        u64 pk[2][4];
#pragma unroll
        for (int qg = 0; qg < 2; qg++) {
            float sv[4][4];
#pragma unroll
            for (int nb = 0; nb < 4; nb++) {
                f32x4 a = {};
#pragma unroll
                for (int ks = 0; ks < 4; ks++) {
                    bf8_t kf = *(const bf8_t*)&Kt[(nb * 16 + lm) * 136 + ks * 32 + lq * 8];
                    a = mfma16(kf, qf[qg][ks], a);
                }
#pragma unroll
                for (int r = 0; r < 4; r++) sv[nb][r] = a[r] * ATT_SCALE;
            }
            if (kt >= 2 * qt + qg) {
                int qglob = q0 + qg * 64 + wave * 16 + lm;
#pragma unroll
                for (int nb = 0; nb < 4; nb++)
#pragma unroll
                    for (int r = 0; r < 4; r++)
                        if (kt * 64 + nb * 16 + lq * 4 + r > qglob) sv[nb][r] = -3.0e38f;
            }
            float mx = -3.0e38f;
#pragma unroll
            for (int nb = 0; nb < 4; nb++)
#pragma unroll
                for (int r = 0; r < 4; r++) mx = fmaxf(mx, sv[nb][r]);
            mx = fmaxf(mx, __shfl_xor(mx, 16, 64));
            mx = fmaxf(mx, __shfl_xor(mx, 32, 64));
            float mnew = fmaxf(mrun[qg], mx);
            float a_ = __expf(mrun[qg] - mnew);
            float rs = 0.f;
#pragma unroll
            for (int nb = 0; nb < 4; nb++) {
                float e0 = __expf(sv[nb][0] - mnew), e1 = __expf(sv[nb][1] - mnew);
                float e2 = __expf(sv[nb][2] - mnew), e3 = __expf(sv[nb][3] - mnew);
                rs += (e0 + e1) + (e2 + e3);
                unsigned int lo = (unsigned int)f2b(e0) | ((unsigned int)f2b(e1) << 16);
                unsigned int hi = (unsigned int)f2b(e2) | ((unsigned int)f2b(e3) << 16);
                pk[qg][nb] = (u64)lo | ((u64)hi << 32);
            }
            rs += __shfl_xor(rs, 16, 64);
            rs += __shfl_xor(rs, 32, 64);
            lrun[qg] = lrun[qg] * a_ + rs;
            mrun[qg] = mnew;
#pragma unroll
            for (int db = 0; db < 8; db++)
#pragma unroll
                for (int r = 0; r < 4; r++) Of[qg][db][r] *= a_;
        }

        const int slo = ((lq & 1) * 2) * 16 + lm;
        const int shi = slo + 16;
        const bool sel = (lq >> 1) != 0;
#pragma unroll
        for (int kk = 0; kk < 2; kk++) {
            union { u64 v[2]; bf8_t f; } pf[2];
#pragma unroll
            for (int qg = 0; qg < 2; qg++) {
                u64 lo0 = __shfl(pk[qg][2 * kk + 0], slo, 64);
                u64 lo1 = __shfl(pk[qg][2 * kk + 1], slo, 64);
                u64 hi0 = __shfl(pk[qg][2 * kk + 0], shi, 64);
                u64 hi1 = __shfl(pk[qg][2 * kk + 1], shi, 64);
                pf[qg].v[0] = sel ? lo1 : lo0;
                pf[qg].v[1] = sel ? hi1 : hi0;
            }
#pragma unroll
            for (int db = 0; db < 8; db++) {
                bf8_t vf = *(const bf8_t*)&Vt[(db * 16 + lm) * 72 + kk * 32 + lq * 8];
                Of[0][db] = mfma16(vf, pf[0].f, Of[0][db]);
                Of[1][db] = mfma16(vf, pf[1].f, Of[1][db]);
            }
        }
    }
#pragma unroll
    for (int qg = 0; qg < 2; qg++) {
        float invl = 1.f / lrun[qg];
        size_t rowbase = (size_t)(b * 2048 + q0 + qg * 64 + wave * 16 + lm) * 2048 + h * 128;
#pragma unroll
        for (int db = 0; db < 8; db++) {
            ushort4 o;
            o.x = f2b(Of[qg][db][0] * invl);
            o.y = f2b(Of[qg][db][1] * invl);
            o.z = f2b(Of[qg][db][2] * invl);
            o.w = f2b(Of[qg][db][3] * invl);
            *(ushort4*)(AO + rowbase + db * 16 + lq * 4) = o;
        }
    }
}

extern "C" void kernel_launch(void* const* d_in, const int* in_sizes, int n_in,
                              void* d_out, int out_size, void* d_ws, size_t ws_size,
                              hipStream_t stream) {
    const float* x     = (const float*)d_in[0];
    const float* w_qkv = (const float*)d_in[1];
    const float* w_o   = (const float*)d_in[2];
    float* out = (float*)d_out;
    u16* ws = (u16*)d_ws;

    u16* qkvb  = ws;                    // 25,165,824
    u16* VT    = ws + 25165824;         //  8,388,608
    u16* AO    = ws + 33554432;         //  8,388,608
    u16* xb    = ws + 41943040;         //  8,388,608
    u16* wqkvb = ws + 50331648;         // 12,582,912
    u16* wob   = ws + 62914560;         //  4,194,304

    cvt_all<<<12288, 256, 0, stream>>>(x, w_qkv, w_o, xb, wqkvb, wob);
    gemm32<0><<<dim3(48, 32), 256, 0, stream>>>(xb, wqkvb, qkvb, 4096, 6144, 2048, 6144);
    transpose_v<<<dim3(32, 32), 256, 0, stream>>>(qkvb, VT);
    attn_flash<<<dim3(32, 16), 256, 0, stream>>>(qkvb, VT, AO);
    gemm32<1><<<dim3(16, 32), 256, 0, stream>>>(AO, wob, out, 4096, 2048, 2048, 2048);
}